// Round 8
// baseline (853.549 us; speedup 1.0000x reference)
//
#include <hip/hip_runtime.h>
#include <math.h>

#define NN 30000
#define NE 480000
#define PN 512   // probe rows

typedef _Float16 f16x8 __attribute__((ext_vector_type(8)));
typedef _Float16 f16x4 __attribute__((ext_vector_type(4)));
typedef float f32x4 __attribute__((ext_vector_type(4)));

// ---------------- utility ----------------
__global__ void zero_int_kernel(int* p, int n) {
    int i = blockIdx.x * blockDim.x + threadIdx.x;
    if (i < n) p[i] = 0;
}
__global__ void zero_float_kernel(float* p, int n) {
    int i = blockIdx.x * blockDim.x + threadIdx.x;
    if (i < n) p[i] = 0.0f;
}

// ---------------- CSR build (verified) ----------------
__global__ void deg_kernel(const int* __restrict__ dst, int* __restrict__ deg, int e) {
    int i = blockIdx.x * blockDim.x + threadIdx.x;
    if (i < e) atomicAdd(&deg[dst[i]], 1);
}

__global__ void scan_kernel(const int* __restrict__ deg, int* __restrict__ row_start,
                            int* __restrict__ pos, int n) {
    __shared__ int smem[1024];
    __shared__ int carry;
    if (threadIdx.x == 0) carry = 0;
    __syncthreads();
    for (int base = 0; base < n; base += 1024) {
        int i = base + threadIdx.x;
        int v = (i < n) ? deg[i] : 0;
        smem[threadIdx.x] = v;
        __syncthreads();
        for (int off = 1; off < 1024; off <<= 1) {
            int t = 0;
            if ((int)threadIdx.x >= off) t = smem[threadIdx.x - off];
            __syncthreads();
            smem[threadIdx.x] += t;
            __syncthreads();
        }
        int excl = smem[threadIdx.x] - v;
        if (i < n) {
            int r = carry + excl;
            row_start[i] = r;
            pos[i] = r;
        }
        __syncthreads();
        if (threadIdx.x == 0) carry += smem[1023];
        __syncthreads();
    }
    if (threadIdx.x == 0) row_start[n] = carry;
}

__global__ void fill_kernel(const int* __restrict__ src, const int* __restrict__ dst,
                            int* __restrict__ pos, int* __restrict__ csr_src, int e) {
    int i = blockIdx.x * blockDim.x + threadIdx.x;
    if (i < e) {
        int p = atomicAdd(&pos[dst[i]], 1);
        csr_src[p] = src[i];
    }
}

// ---------------- conversions ----------------
__global__ void cvt_f32_f16_kernel(const float* __restrict__ in, _Float16* __restrict__ out, long n8) {
    long i = blockIdx.x * (long)blockDim.x + threadIdx.x;
    if (i >= n8) return;
    float4 a = ((const float4*)in)[2 * i];
    float4 b = ((const float4*)in)[2 * i + 1];
    f16x8 o = {(_Float16)a.x, (_Float16)a.y, (_Float16)a.z, (_Float16)a.w,
               (_Float16)b.x, (_Float16)b.y, (_Float16)b.z, (_Float16)b.w};
    ((f16x8*)out)[i] = o;
}

// strided-input transpose+cast: outT[n*K + k] = f16(in[k*ldin + n])
__global__ void tcvt_s_kernel(const float* __restrict__ in, int ldin,
                              _Float16* __restrict__ outT, int K, int N) {
    int n = blockIdx.x * blockDim.x + threadIdx.x;
    int k = blockIdx.y;
    if (n < N) outT[(long)n * K + k] = (_Float16)in[(long)k * ldin + n];
}

// f16 block-diag BT (probe path, verified): outT[e*256+d] = krel[h][d&63][e&63] if same head
__global__ void bdcvt_kernel(const float* __restrict__ krel, _Float16* __restrict__ outT) {
    int idx = blockIdx.x * blockDim.x + threadIdx.x;  // 65536
    int e = idx >> 8, d = idx & 255;
    int he = e >> 6, hd = d >> 6;
    float v = (he == hd) ? krel[he * 4096 + (d & 63) * 64 + (e & 63)] : 0.0f;
    outT[idx] = (_Float16)v;
}

// fp32 block-diag (row-major, NOT transposed): BD[d*256+e] = krel[h][d&63][e&63]
__global__ void bdf32_kernel(const float* __restrict__ krel, float* __restrict__ BD) {
    int idx = blockIdx.x * blockDim.x + threadIdx.x;  // 65536
    int d = idx >> 8, e = idx & 255;
    float v = ((d >> 6) == (e >> 6)) ? krel[(d >> 6) * 4096 + (d & 63) * 64 + (e & 63)] : 0.0f;
    BD[idx] = v;
}

// fused bias: out[0:256)=b[0:256]@BDk, [256:512)=b, [512:768)=b[512:768]@BDv
__global__ void bias_fuse_kernel(const float* __restrict__ b, const float* __restrict__ BDk,
                                 const float* __restrict__ BDv, float* __restrict__ out) {
    int j = blockIdx.x * blockDim.x + threadIdx.x;
    if (j >= 768) return;
    if (j < 256) {
        float s = 0;
        for (int d = 0; d < 256; ++d) s += b[d] * BDk[d * 256 + j];
        out[j] = s;
    } else if (j < 512) {
        out[j] = b[j];
    } else {
        float s = 0; int e = j - 512;
        for (int d = 0; d < 256; ++d) s += b[512 + d] * BDv[d * 256 + e];
        out[j] = s;
    }
}

// ---------------- fp32 GEMM (weight fusion + probe ref) ----------------
__global__ __launch_bounds__(256) void gemm_f32_kernel(
    const float* __restrict__ A, int lda, long sA,
    const float* __restrict__ B, int ldb, long sB,
    float* __restrict__ C, int ldc, long sC,
    int M, int N, int K,
    const float* __restrict__ bias,
    const float* __restrict__ res,
    const float* __restrict__ skip)
{
    __shared__ float As[16][68];
    __shared__ float Bs[16][68];
    const int tid = threadIdx.x;
    const int tx = tid & 15, ty = tid >> 4;
    const int bn = blockIdx.x * 64, bm = blockIdx.y * 64;
    const int bz = blockIdx.z;
    A += (long)bz * sA; B += (long)bz * sB; C += (long)bz * sC;
    const int ar = tid >> 2, ak0 = (tid & 3) << 2;
    const int bk = tid >> 4, bc0 = (tid & 15) << 2;

    float acc[4][4] = {};
    for (int k0 = 0; k0 < K; k0 += 16) {
        float4 av = make_float4(0.f, 0.f, 0.f, 0.f);
        int grow = bm + ar;
        if (grow < M) av = *(const float4*)(A + (long)grow * lda + k0 + ak0);
        As[ak0 + 0][ar] = av.x;
        As[ak0 + 1][ar] = av.y;
        As[ak0 + 2][ar] = av.z;
        As[ak0 + 3][ar] = av.w;
        *(float4*)&Bs[bk][bc0] = *(const float4*)(B + (long)(k0 + bk) * ldb + bn + bc0);
        __syncthreads();
#pragma unroll
        for (int kk = 0; kk < 16; ++kk) {
            float4 a = *(const float4*)&As[kk][ty << 2];
            float4 b4 = *(const float4*)&Bs[kk][tx << 2];
            acc[0][0] += a.x * b4.x; acc[0][1] += a.x * b4.y; acc[0][2] += a.x * b4.z; acc[0][3] += a.x * b4.w;
            acc[1][0] += a.y * b4.x; acc[1][1] += a.y * b4.y; acc[1][2] += a.y * b4.z; acc[1][3] += a.y * b4.w;
            acc[2][0] += a.z * b4.x; acc[2][1] += a.z * b4.y; acc[2][2] += a.z * b4.z; acc[2][3] += a.z * b4.w;
            acc[3][0] += a.w * b4.x; acc[3][1] += a.w * b4.y; acc[3][2] += a.w * b4.z; acc[3][3] += a.w * b4.w;
        }
        __syncthreads();
    }
#pragma unroll
    for (int i = 0; i < 4; ++i) {
        int row = bm + (ty << 2) + i;
        if (row >= M) continue;
#pragma unroll
        for (int j = 0; j < 4; ++j) {
            int col = bn + (tx << 2) + j;
            float v = acc[i][j];
            if (bias) v += bias[col];
            C[(long)row * ldc + col] = v;
        }
    }
}

// ---------------- fp16 MFMA GEMM (verified engine) ----------------
__global__ __launch_bounds__(256) void mfma_gemm_kernel(
    const _Float16* __restrict__ A, int lda,
    const _Float16* __restrict__ BT,
    float* __restrict__ Cf,
    _Float16* __restrict__ Ch,
    int ldc, int M, int N, int K,
    const float* __restrict__ bias,
    const float* __restrict__ res,
    const float* __restrict__ skip)
{
    __shared__ __align__(16) _Float16 As[128][40];
    __shared__ __align__(16) _Float16 Bs[128][40];
    const int tid = threadIdx.x;
    const int bm = blockIdx.y * 128, bn = blockIdx.x * 128;
    const int wave = tid >> 6, lane = tid & 63;
    const int wr = wave >> 1, wc = wave & 1;
    const int l16 = lane & 15, quad = lane >> 4;

    f32x4 acc[4][4] = {};

    for (int k0 = 0; k0 < K; k0 += 32) {
#pragma unroll
        for (int c = 0; c < 2; ++c) {
            int chunk = tid + c * 256;
            int row = chunk >> 2, kc = (chunk & 3) << 3;
            f16x8 av = {};
            int gr = bm + row;
            if (gr < M) av = *(const f16x8*)(A + (long)gr * lda + k0 + kc);
            *(f16x8*)&As[row][kc] = av;
            f16x8 bv = {};
            int gn = bn + row;
            if (gn < N) bv = *(const f16x8*)(BT + (long)gn * K + k0 + kc);
            *(f16x8*)&Bs[row][kc] = bv;
        }
        __syncthreads();
        f16x8 af[4], bf[4];
#pragma unroll
        for (int i = 0; i < 4; ++i)
            af[i] = *(const f16x8*)&As[64 * wr + 16 * i + l16][quad * 8];
#pragma unroll
        for (int j = 0; j < 4; ++j)
            bf[j] = *(const f16x8*)&Bs[64 * wc + 16 * j + l16][quad * 8];
#pragma unroll
        for (int i = 0; i < 4; ++i)
#pragma unroll
            for (int j = 0; j < 4; ++j)
                acc[i][j] = __builtin_amdgcn_mfma_f32_16x16x32_f16(af[i], bf[j], acc[i][j], 0, 0, 0);
        __syncthreads();
    }

    float s = 1.0f, om = 0.0f;
    if (skip) {
        float sv = 1.0f / (1.0f + __expf(-skip[0]));
        s = sv; om = 1.0f - sv;
    }
#pragma unroll
    for (int i = 0; i < 4; ++i) {
        int gr0 = bm + 64 * wr + 16 * i + quad * 4;
#pragma unroll
        for (int j = 0; j < 4; ++j) {
            int gc = bn + 64 * wc + 16 * j + l16;
            float bv = bias ? bias[gc] : 0.0f;
#pragma unroll
            for (int r = 0; r < 4; ++r) {
                int row = gr0 + r;
                if (row >= M) continue;
                float v = acc[i][j][r] + bv;
                if (res) v = s * v + om * res[(long)row * ldc + gc];
                if (Cf) Cf[(long)row * ldc + gc] = v;
                if (Ch) Ch[(long)row * ldc + gc] = (_Float16)v;
            }
        }
    }
}

// ---------------- attention: f16 q/kp/vp (stride ldkv), prefetch pipeline,
// fused exact GELU, f16 out (r7-verified math, + ldkv + prefetch) ----------------
template <int H>
__global__ __launch_bounds__(256) void attn_f16kv_kernel(
    const _Float16* __restrict__ qbase, int ldq,
    const _Float16* __restrict__ kp, const _Float16* __restrict__ vp, int ldkv,
    const float* __restrict__ p_rel,
    const int* __restrict__ row_start, const int* __restrict__ csr_src,
    _Float16* __restrict__ agg, int n)
{
    constexpr int D = 256 / H;
    constexpr int GL = D / 8;  // lanes per head group (8 ch per lane)
    int node = blockIdx.x * 8 + (threadIdx.x >> 5);
    int l32 = threadIdx.x & 31;
    if (node >= n) return;
    const int head = l32 / GL;
    const float scale = p_rel[head] * rsqrtf((float)D);
    const int ch = l32 * 8;
    f16x8 qv = *(const f16x8*)(qbase + (long)node * ldq + ch);
    float q[8];
#pragma unroll
    for (int j = 0; j < 8; ++j) q[j] = (float)qv[j];
    int e0 = row_start[node], e1 = row_start[node + 1];
    float m = -1e30f, lsum = 0.0f;
    float a[8] = {};
    if (e0 < e1) {
        int src = csr_src[e0];
        f16x8 kv = *(const f16x8*)(kp + (long)src * ldkv + ch);
        f16x8 vv = *(const f16x8*)(vp + (long)src * ldkv + ch);
        for (int e = e0; e < e1; ++e) {
            int nsrc = (e + 1 < e1) ? csr_src[e + 1] : src;
            f16x8 kvn = *(const f16x8*)(kp + (long)nsrc * ldkv + ch);
            f16x8 vvn = *(const f16x8*)(vp + (long)nsrc * ldkv + ch);
            float d = 0.0f;
#pragma unroll
            for (int j = 0; j < 8; ++j) d += q[j] * (float)kv[j];
#pragma unroll
            for (int off = 1; off < GL; off <<= 1) d += __shfl_xor(d, off);
            float alpha = d * scale;
            float m_new = fmaxf(m, alpha);
            float corr = __expf(m - m_new);
            float w = __expf(alpha - m_new);
            lsum = lsum * corr + w;
#pragma unroll
            for (int j = 0; j < 8; ++j) a[j] = a[j] * corr + w * (float)vv[j];
            m = m_new;
            kv = kvn; vv = vvn;
        }
    }
    float inv = 1.0f / (lsum + 1e-16f);
    f16x8 o;
#pragma unroll
    for (int j = 0; j < 8; ++j) {
        float v = a[j] * inv;
        v = 0.5f * v * (1.0f + erff(v * 0.70710678118654752f));
        o[j] = (_Float16)v;
    }
    *(f16x8*)(agg + (long)node * 256 + ch) = o;
}

// ---------------- BatchNorm (verified) ----------------
__global__ void bn_stats_kernel(const float* __restrict__ h, float* __restrict__ sums,
                                float* __restrict__ sqs, int n) {
    int c = threadIdx.x;
    float s = 0.f, q = 0.f;
    for (int r = blockIdx.x; r < n; r += gridDim.x) {
        float v = h[(long)r * 256 + c];
        s += v;
        q += v * v;
    }
    atomicAdd(&sums[c], s);
    atomicAdd(&sqs[c], q);
}

__global__ void bn_apply_kernel(float* __restrict__ h, _Float16* __restrict__ oh,
                                const float* __restrict__ sums, const float* __restrict__ sqs,
                                const float* __restrict__ gamma, const float* __restrict__ beta) {
    long idx = blockIdx.x * (long)blockDim.x + threadIdx.x;
    if (idx >= (long)NN * 64) return;
    int cg = (int)(idx & 63) * 4;
    float4 hv = ((float4*)h)[idx];
    float vv[4] = {hv.x, hv.y, hv.z, hv.w};
    const float invn = 1.0f / 30000.0f;
    f16x4 ovh;
#pragma unroll
    for (int r = 0; r < 4; ++r) {
        int c = cg + r;
        float mu = sums[c] * invn;
        float var = sqs[c] * invn - mu * mu;
        float v = (vv[r] - mu) * rsqrtf(var + 1e-5f) * gamma[c] + beta[c];
        v = fmaxf(v, 0.0f);
        vv[r] = v;
        ovh[r] = (_Float16)v;
    }
    ((float4*)h)[idx] = make_float4(vv[0], vv[1], vv[2], vv[3]);
    ((f16x4*)oh)[idx] = ovh;
}

// ---------------- probe compare + sentinel ----------------
__global__ void cmp_f16_kernel(const float* __restrict__ ref, int ldr,
                               const _Float16* __restrict__ val, int ldv,
                               int rows, int cols, float tol, int* __restrict__ flag) {
    long i = blockIdx.x * (long)blockDim.x + threadIdx.x;
    if (i >= (long)rows * cols) return;
    long r = i / cols; int c = (int)(i % cols);
    float d = fabsf(ref[r * ldr + c] - (float)val[r * ldv + c]);
    if (d > tol) atomicOr(flag, 1);
}
__global__ void sentinel_kernel(float* __restrict__ out, const int* __restrict__ flags) {
    if (blockIdx.x == 0 && threadIdx.x == 0)
        out[0] += 1000.0f * flags[0] + 2000.0f * flags[1];
}

// ---------------- launch ----------------
extern "C" void kernel_launch(void* const* d_in, const int* in_sizes, int n_in,
                              void* d_out, int out_size, void* d_ws, size_t ws_size,
                              hipStream_t stream) {
    const float* x       = (const float*)d_in[0];
    const int*   ei      = (const int*)d_in[1];
    const float* w_kqv1  = (const float*)d_in[2];
    const float* b_kqv1  = (const float*)d_in[3];
    const float* k_rel1  = (const float*)d_in[4];
    const float* v_rel1  = (const float*)d_in[5];
    const float* p_rel1  = (const float*)d_in[6];
    const float* w_out1  = (const float*)d_in[7];
    const float* b_out1  = (const float*)d_in[8];
    const float* bn_gamma = (const float*)d_in[10];
    const float* bn_beta  = (const float*)d_in[11];
    const float* w_kqv2  = (const float*)d_in[12];
    const float* b_kqv2  = (const float*)d_in[13];
    const float* k_rel2  = (const float*)d_in[14];
    const float* v_rel2  = (const float*)d_in[15];
    const float* p_rel2  = (const float*)d_in[16];
    const float* w_out2  = (const float*)d_in[17];
    const float* b_out2  = (const float*)d_in[18];
    const float* skip2   = (const float*)d_in[19];
    float* out = (float*)d_out;

    char* p = (char*)d_ws;
    auto alloc = [&](size_t bytes) -> void* {
        void* r = (void*)p;
        p += (bytes + 255) & ~(size_t)255;
        return r;
    };
    // ~145 MB total, no aliasing
    _Float16* x_h   = (_Float16*)alloc((size_t)NN * 512 * 2);
    _Float16* kqv_h = (_Float16*)alloc((size_t)NN * 768 * 2);   // [kp | q | vp] f16
    _Float16* agg_h = (_Float16*)alloc((size_t)NN * 256 * 2);
    float*    h     = (float*)alloc((size_t)NN * 256 * 4);
    _Float16* hbn_h = (_Float16*)alloc((size_t)NN * 256 * 2);
    _Float16* BT1    = (_Float16*)alloc((size_t)768 * 512 * 2);
    _Float16* BT2    = (_Float16*)alloc((size_t)768 * 256 * 2);
    _Float16* wout1T = (_Float16*)alloc((size_t)256 * 256 * 2);
    _Float16* wout2T = (_Float16*)alloc((size_t)256 * 256 * 2);
    float* BD1k  = (float*)alloc((size_t)256 * 256 * 4);
    float* BD1v  = (float*)alloc((size_t)256 * 256 * 4);
    float* Fa    = (float*)alloc((size_t)512 * 256 * 4);  // fusion scratch
    float* Fb    = (float*)alloc((size_t)512 * 256 * 4);
    float* bias1 = (float*)alloc(768 * 4);
    float* bias2 = (float*)alloc(768 * 4);
    // probe buffers
    _Float16* wkT    = (_Float16*)alloc((size_t)256 * 512 * 2);
    _Float16* wk2T   = (_Float16*)alloc((size_t)256 * 256 * 2);
    _Float16* bd1k_h = (_Float16*)alloc((size_t)256 * 256 * 2);
    _Float16* krel2T = (_Float16*)alloc((size_t)256 * 256 * 2);
    _Float16* ktmp_h = (_Float16*)alloc((size_t)PN * 256 * 2);
    float*    kpold  = (float*)alloc((size_t)PN * 256 * 4);
    int*   deg       = (int*)alloc((size_t)NN * 4);
    int*   row_start = (int*)alloc((size_t)(NN + 1) * 4);
    int*   pos       = (int*)alloc((size_t)NN * 4);
    int*   csr_src   = (int*)alloc((size_t)NE * 4);
    float* bnsum     = (float*)alloc(256 * 4);
    float* bnsq      = (float*)alloc(256 * 4);
    int*   flags     = (int*)alloc(256);

    const int* esrc = ei;
    const int* edst = ei + NE;

    zero_int_kernel<<<1, 64, 0, stream>>>(flags, 2);

    // ---- input cast ----
    cvt_f32_f16_kernel<<<(NN * 512 / 8 + 255) / 256, 256, 0, stream>>>(x, x_h, (long)NN * 512 / 8);

    // ---- layer-1 weight fusion (fp32): F = W @ KrelBD, then BT1 = [FkT; WqT; FvT] f16 ----
    bdf32_kernel<<<256, 256, 0, stream>>>(k_rel1, BD1k);
    bdf32_kernel<<<256, 256, 0, stream>>>(v_rel1, BD1v);
    gemm_f32_kernel<<<dim3(4, 8), 256, 0, stream>>>(
        w_kqv1, 768, 0, BD1k, 256, 0, Fa, 256, 0, 512, 256, 256, nullptr, nullptr, nullptr);
    gemm_f32_kernel<<<dim3(4, 8), 256, 0, stream>>>(
        w_kqv1 + 512, 768, 0, BD1v, 256, 0, Fb, 256, 0, 512, 256, 256, nullptr, nullptr, nullptr);
    tcvt_s_kernel<<<dim3(1, 512), 256, 0, stream>>>(Fa, 256, BT1, 512, 256);
    tcvt_s_kernel<<<dim3(1, 512), 256, 0, stream>>>(w_kqv1 + 256, 768, BT1 + 256 * 512, 512, 256);
    tcvt_s_kernel<<<dim3(1, 512), 256, 0, stream>>>(Fb, 256, BT1 + 512 * 512, 512, 256);
    bias_fuse_kernel<<<3, 256, 0, stream>>>(b_kqv1, BD1k, BD1v, bias1);

    // ---- layer-2 weight fusion (k_rel2/v_rel2 are full [256,256]) ----
    gemm_f32_kernel<<<dim3(4, 4), 256, 0, stream>>>(
        w_kqv2, 768, 0, k_rel2, 256, 0, Fa, 256, 0, 256, 256, 256, nullptr, nullptr, nullptr);
    gemm_f32_kernel<<<dim3(4, 4), 256, 0, stream>>>(
        w_kqv2 + 512, 768, 0, v_rel2, 256, 0, Fb, 256, 0, 256, 256, 256, nullptr, nullptr, nullptr);
    tcvt_s_kernel<<<dim3(1, 256), 256, 0, stream>>>(Fa, 256, BT2, 256, 256);
    tcvt_s_kernel<<<dim3(1, 256), 256, 0, stream>>>(w_kqv2 + 256, 768, BT2 + 256 * 256, 256, 256);
    tcvt_s_kernel<<<dim3(1, 256), 256, 0, stream>>>(Fb, 256, BT2 + 512 * 256, 256, 256);
    bias_fuse_kernel<<<3, 256, 0, stream>>>(b_kqv2, k_rel2, v_rel2, bias2);

    // ---- other weights ----
    tcvt_s_kernel<<<dim3(1, 256), 256, 0, stream>>>(w_out1, 256, wout1T, 256, 256);
    tcvt_s_kernel<<<dim3(1, 256), 256, 0, stream>>>(w_out2, 256, wout2T, 256, 256);
    // probe weights (old two-step path)
    tcvt_s_kernel<<<dim3(1, 512), 256, 0, stream>>>(w_kqv1, 768, wkT, 512, 256);
    bdcvt_kernel<<<256, 256, 0, stream>>>(k_rel1, bd1k_h);
    tcvt_s_kernel<<<dim3(1, 256), 256, 0, stream>>>(w_kqv2, 768, wk2T, 256, 256);
    tcvt_s_kernel<<<dim3(1, 256), 256, 0, stream>>>(k_rel2, 256, krel2T, 256, 256);

    // ---- CSR build ----
    zero_int_kernel<<<(NN + 255) / 256, 256, 0, stream>>>(deg, NN);
    deg_kernel<<<(NE + 255) / 256, 256, 0, stream>>>(edst, deg, NE);
    scan_kernel<<<1, 1024, 0, stream>>>(deg, row_start, pos, NN);
    fill_kernel<<<(NE + 255) / 256, 256, 0, stream>>>(esrc, edst, pos, csr_src, NE);

    const int MB = (NN + 127) / 128;

    // ---- layer 1: ONE fused GEMM -> [kp | q | vp] ----
    mfma_gemm_kernel<<<dim3(6, MB), 256, 0, stream>>>(
        x_h, 512, BT1, nullptr, kqv_h, 768, NN, 768, 512, bias1, nullptr, nullptr);
    // PROBE L1: old two-step kp on PN rows
    mfma_gemm_kernel<<<dim3(2, 4), 256, 0, stream>>>(
        x_h, 512, wkT, nullptr, ktmp_h, 256, PN, 256, 512, b_kqv1, nullptr, nullptr);
    mfma_gemm_kernel<<<dim3(2, 4), 256, 0, stream>>>(
        ktmp_h, 256, bd1k_h, kpold, nullptr, 256, PN, 256, 256, nullptr, nullptr, nullptr);
    cmp_f16_kernel<<<(PN * 256 + 255) / 256, 256, 0, stream>>>(
        kpold, 256, kqv_h, 768, PN, 256, 0.15f, &flags[0]);

    attn_f16kv_kernel<4><<<(NN + 7) / 8, 256, 0, stream>>>(
        kqv_h + 256, 768, kqv_h, kqv_h + 512, 768, p_rel1, row_start, csr_src, agg_h, NN);

    mfma_gemm_kernel<<<dim3(2, MB), 256, 0, stream>>>(
        agg_h, 256, wout1T, h, nullptr, 256, NN, 256, 256, b_out1, nullptr, nullptr);

    // ---- BatchNorm + ReLU ----
    zero_float_kernel<<<1, 256, 0, stream>>>(bnsum, 256);
    zero_float_kernel<<<1, 256, 0, stream>>>(bnsq, 256);
    bn_stats_kernel<<<256, 256, 0, stream>>>(h, bnsum, bnsq, NN);
    bn_apply_kernel<<<(NN * 64 + 255) / 256, 256, 0, stream>>>(h, hbn_h, bnsum, bnsq, bn_gamma, bn_beta);

    // ---- layer 2: ONE fused GEMM ----
    mfma_gemm_kernel<<<dim3(6, MB), 256, 0, stream>>>(
        hbn_h, 256, BT2, nullptr, kqv_h, 768, NN, 768, 256, bias2, nullptr, nullptr);
    // PROBE L2
    mfma_gemm_kernel<<<dim3(2, 4), 256, 0, stream>>>(
        hbn_h, 256, wk2T, nullptr, ktmp_h, 256, PN, 256, 256, b_kqv2, nullptr, nullptr);
    mfma_gemm_kernel<<<dim3(2, 4), 256, 0, stream>>>(
        ktmp_h, 256, krel2T, kpold, nullptr, 256, PN, 256, 256, nullptr, nullptr, nullptr);
    cmp_f16_kernel<<<(PN * 256 + 255) / 256, 256, 0, stream>>>(
        kpold, 256, kqv_h, 768, PN, 256, 0.15f, &flags[1]);

    attn_f16kv_kernel<1><<<(NN + 7) / 8, 256, 0, stream>>>(
        kqv_h + 256, 768, kqv_h, kqv_h + 512, 768, p_rel2, row_start, csr_src, agg_h, NN);

    // out2 + skip
    mfma_gemm_kernel<<<dim3(2, MB), 256, 0, stream>>>(
        agg_h, 256, wout2T, out, nullptr, 256, NN, 256, 256, b_out2, h, skip2);

    // ---- sentinel ----
    sentinel_kernel<<<1, 64, 0, stream>>>(out, flags);
}